// Round 5
// baseline (295.645 us; speedup 1.0000x reference)
//
#include <hip/hip_runtime.h>
#include <hip/hip_bf16.h>
#include <math.h>

#define FLn 96
#define SEG 288      // 3*FL
#define EPRE_DIM 192 // 2*FL
#define EPS_BN 1e-5f

typedef __attribute__((ext_vector_type(8))) short short8;
typedef __attribute__((ext_vector_type(4))) float floatx4;
typedef float v2f __attribute__((ext_vector_type(2)));

__device__ __forceinline__ float lrelu(float v) { return fmaxf(v, 0.1f * v); }

// ---------------- K0: cast GEMM weights to bf16 ([out][k] layout kept) ------
__global__ __launch_bounds__(256) void k0_cast(
    const float* __restrict__ rsW, const float* __restrict__ clW1,
    __hip_bfloat16* __restrict__ wB2, __hip_bfloat16* __restrict__ wB3) {
  int idx = blockIdx.x * 256 + threadIdx.x;
  int stride = gridDim.x * 256;
  for (int i = idx; i < 288 * 192; i += stride) wB2[i] = __float2bfloat16(rsW[i]);
  for (int i = idx; i < 288 * 576; i += stride) wB3[i] = __float2bfloat16(clW1[i]);
}

// ---------------- K1: per-(sample,half) fusion front-end -> e_pre(192) bf16 -
// Rank-2 factorization: lrelu(arm_i*x86_j) = aP_i*xp_j + aN_i*xn_j (exact).
// Pre-convolved CP[di][j] = conv1d(xp, w_row_di), CN likewise. Each fe element
// = 6 FMAs, packed as v_pk_fma_f32 (2 cols/op).
__global__ __launch_bounds__(256) void k1_persample(
    const float* __restrict__ x,
    const float* __restrict__ cw1, const float* __restrict__ cb1,
    const float* __restrict__ cw2, const float* __restrict__ cb2,
    const float* __restrict__ cw3, const float* __restrict__ cb3,
    const float* __restrict__ cw4, const float* __restrict__ cb4,
    const float* __restrict__ cw5, const float* __restrict__ cb5,
    const float* __restrict__ cw6, const float* __restrict__ cb6,
    const float* __restrict__ deW, const float* __restrict__ deb,
    __hip_bfloat16* __restrict__ epre) {
  __shared__ float c_in[SEG];
  __shared__ float st1[SEG];
  __shared__ float pk4[4 * 98];   // aPp | aNp | xpP | xnP (each padded 0..97)
  __shared__ float bert[FLn];
  __shared__ float CPa[3 * FLn];
  __shared__ float CNa[3 * FLn];
  __shared__ float wker[9];
  __shared__ float colpart[32 * 98];
  __shared__ float ep[EPRE_DIM];

  const int tid = threadIdx.x;
  const int bid = blockIdx.x;          // m = samp*2 + half
  const float* xrow = x + (bid >> 1) * 576 + (bid & 1) * 288;

  float* aPp = pk4;
  float* aNp = pk4 + 98;
  float* xpP = pk4 + 196;
  float* xnP = pk4 + 294;

  // zero the 8 pad slots (indices never written by stage-2)
  if (tid < 8) pk4[(tid >> 1) * 98 + (tid & 1) * 97] = 0.f;

  const float a0w0 = cw1[0], a0w1 = cw1[1], a0w2 = cw1[2], a0b = cb1[0];
  const float a1w0 = cw2[0], a1w1 = cw2[1], a1w2 = cw2[2], a1b = cb2[0];
  const float a2w0 = cw3[0], a2w1 = cw3[1], a2w2 = cw3[2], a2b = cb3[0];
  const float b0w0 = cw4[0], b0w1 = cw4[1], b0w2 = cw4[2], b0b = cb4[0];
  const float b1w0 = cw5[0], b1w1 = cw5[1], b1w2 = cw5[2], b1b = cb5[0];
  const float b2w0 = cw6[0], b2w1 = cw6[1], b2w2 = cw6[2], b2b = cb6[0];

  if (tid < 72) ((float4*)c_in)[tid] = ((const float4*)xrow)[tid];
  __syncthreads();

  // stage-1 convs
  for (int t = tid; t < SEG; t += 256) {
    bool g1 = t >= 96, g2 = t >= 192;
    float wa = g2 ? a2w0 : (g1 ? a1w0 : a0w0);
    float wb = g2 ? a2w1 : (g1 ? a1w1 : a0w1);
    float wc = g2 ? a2w2 : (g1 ? a1w2 : a0w2);
    float bb = g2 ? a2b  : (g1 ? a1b  : a0b);
    int p = t - (g2 ? 192 : (g1 ? 96 : 0));
    float l = p > 0 ? c_in[t - 1] : 0.f;
    float m = c_in[t];
    float r = p < FLn - 1 ? c_in[t + 1] : 0.f;
    st1[t] = lrelu(fmaf(wa, l, fmaf(wb, m, fmaf(wc, r, bb))));
  }
  __syncthreads();
  // stage-2 convs -> aP/aN, xp/xn, bert
  for (int t = tid; t < SEG; t += 256) {
    bool g1 = t >= 96, g2 = t >= 192;
    float wa = g2 ? b2w0 : (g1 ? b1w0 : b0w0);
    float wb = g2 ? b2w1 : (g1 ? b1w1 : b0w1);
    float wc = g2 ? b2w2 : (g1 ? b1w2 : b0w2);
    float bb = g2 ? b2b  : (g1 ? b1b  : b0b);
    int p = t - (g2 ? 192 : (g1 ? 96 : 0));
    float l = p > 0 ? st1[t - 1] : 0.f;
    float m = st1[t];
    float r = p < FLn - 1 ? st1[t + 1] : 0.f;
    float v = lrelu(fmaf(wa, l, fmaf(wb, m, fmaf(wc, r, bb))));
    if (!g1) {                      // arm
      aPp[1 + p] = fmaxf(v, 0.1f * v);
      aNp[1 + p] = fminf(v, 0.1f * v);
    } else if (!g2) {               // x86
      xpP[1 + p] = fmaxf(v, 0.f);
      xnP[1 + p] = fminf(v, 0.f);
    } else {                        // bert
      bert[p] = v;
    }
  }
  __syncthreads();
  // per-sample 3x3 kernel: wker = lrelu(bert @ deW.T + deb)
  if (tid < 144) {
    int k9 = tid >> 4, l16 = tid & 15;
    float p = 0.f;
    for (int i = l16; i < FLn; i += 16) p = fmaf(bert[i], deW[k9 * FLn + i], p);
    p += __shfl_down(p, 8, 16);
    p += __shfl_down(p, 4, 16);
    p += __shfl_down(p, 2, 16);
    p += __shfl_down(p, 1, 16);
    if (l16 == 0) wker[k9] = lrelu(p + deb[k9]);
  }
  __syncthreads();
  // column pre-convolutions CP/CN (288 items)
  {
    float w9[9];
#pragma unroll
    for (int q = 0; q < 9; ++q) w9[q] = wker[q];
    for (int t = tid; t < 288; t += 256) {
      int di = t >= 192 ? 2 : (t >= 96 ? 1 : 0);
      int j = t - di * 96;
      float w0 = w9[di * 3 + 0], w1 = w9[di * 3 + 1], w2 = w9[di * 3 + 2];
      CPa[t] = fmaf(w0, xpP[j], fmaf(w1, xpP[j + 1], w2 * xpP[j + 2]));
      CNa[t] = fmaf(w0, xnP[j], fmaf(w1, xnP[j + 1], w2 * xnP[j + 2]));
    }
  }
  __syncthreads();

  // main field: thread tile 3 rows (trr) x 12 cols (tc), packed f32
  const int tc = tid & 7;
  const int trr = tid >> 3;
  const int jb = tc * 12;
  const int ib = trr * 3;

  v2f cp2[18], cn2[18];
#pragma unroll
  for (int di = 0; di < 3; ++di) {
#pragma unroll
    for (int q = 0; q < 3; ++q) {
      float4 t1 = *(const float4*)&CPa[di * 96 + jb + 4 * q];
      cp2[di * 6 + 2 * q]     = (v2f){t1.x, t1.y};
      cp2[di * 6 + 2 * q + 1] = (v2f){t1.z, t1.w};
      float4 t2 = *(const float4*)&CNa[di * 96 + jb + 4 * q];
      cn2[di * 6 + 2 * q]     = (v2f){t2.x, t2.y};
      cn2[di * 6 + 2 * q + 1] = (v2f){t2.z, t2.w};
    }
  }
  float aPv[5], aNv[5];
#pragma unroll
  for (int s = 0; s < 5; ++s) { aPv[s] = aPp[ib + s]; aNv[s] = aNp[ib + s]; }

  v2f cs2[6];
#pragma unroll
  for (int c = 0; c < 6; ++c) cs2[c] = (v2f){0.f, 0.f};

#pragma unroll
  for (int r = 0; r < 3; ++r) {
    v2f rs2 = (v2f){0.f, 0.f};
#pragma unroll
    for (int c = 0; c < 6; ++c) {
      v2f t = aPv[r] * cp2[c];
      t += aPv[r + 1] * cp2[6 + c];
      t += aPv[r + 2] * cp2[12 + c];
      t += aNv[r] * cn2[c];
      t += aNv[r + 1] * cn2[6 + c];
      t += aNv[r + 2] * cn2[12 + c];
      v2f t1 = 0.1f * t;
      v2f f;
      f.x = fmaxf(t.x, t1.x);
      f.y = fmaxf(t.y, t1.y);
      cs2[c] += f;
      rs2 += f;
    }
    float rs = rs2.x + rs2.y;
    rs += __shfl_xor(rs, 1, 64);
    rs += __shfl_xor(rs, 2, 64);
    rs += __shfl_xor(rs, 4, 64);
    if (tc == 0) ep[ib + r] = rs * (1.f / FLn);
  }
  {
    float* cpd = &colpart[trr * 98 + jb];
#pragma unroll
    for (int c = 0; c < 6; ++c) *(v2f*)&cpd[2 * c] = cs2[c];
  }
  __syncthreads();
  if (tid < 48) {
    v2f s = (v2f){0.f, 0.f};
#pragma unroll
    for (int g = 0; g < 32; ++g) s += *(const v2f*)&colpart[g * 98 + 2 * tid];
    s *= (1.f / FLn);
    *(v2f*)&ep[FLn + 2 * tid] = s;
  }
  __syncthreads();
  if (tid < EPRE_DIM) epre[bid * EPRE_DIM + tid] = __float2bfloat16(ep[tid]);
}

// ---------------- K2/K3: bf16 MFMA GEMM, BM=128 BN=32, K-chunk 192 ----------
// A: [M][KTOT] bf16, W: [288][KTOT] bf16. Whole 192-K chunk staged in LDS,
// then 24 barrier-free MFMAs per wave. 64 KB LDS -> 2 blocks/CU.
template <int KTOT, int MODE>
__global__ __launch_bounds__(256) void gemm_mfma(
    const short* __restrict__ A, const short* __restrict__ W,
    const float* __restrict__ bb, const float* __restrict__ gg,
    const float* __restrict__ be, const float* __restrict__ mm,
    const float* __restrict__ vv,
    const float* __restrict__ resid, __hip_bfloat16* __restrict__ out) {
  __shared__ short sA[128 * 200]; // 51.2 KB
  __shared__ short sB[32 * 200];  // 12.8 KB
  const int tid = threadIdx.x;
  const int lane = tid & 63;
  const int w = tid >> 6;
  const int quad = lane >> 4;
  const int l16 = lane & 15;
  const int row0 = (blockIdx.x / 9) * 128;
  const int out0 = (blockIdx.x % 9) * 32;

  const int ar = tid >> 1;       // A row 0..127
  const int ah = tid & 1;        // which 96-short half
  const int br = tid >> 3;       // B row 0..31
  const int bc = (tid & 7) * 3;  // B float4 col base

  floatx4 acc[2][2];
#pragma unroll
  for (int mi = 0; mi < 2; ++mi)
#pragma unroll
    for (int ni = 0; ni < 2; ++ni) acc[mi][ni] = (floatx4){0.f, 0.f, 0.f, 0.f};

#pragma unroll
  for (int kc = 0; kc < KTOT; kc += 192) {
    float4 ra[12];
    const float4* gsrc = (const float4*)&A[(size_t)(row0 + ar) * KTOT + kc + ah * 96];
#pragma unroll
    for (int q = 0; q < 12; ++q) ra[q] = gsrc[q];
    float4 rb[3];
    const float4* gbs = (const float4*)&W[(size_t)(out0 + br) * KTOT + kc + bc * 8];
#pragma unroll
    for (int q = 0; q < 3; ++q) rb[q] = gbs[q];
    __syncthreads();   // previous chunk fully consumed
    {
      float4* da = (float4*)&sA[ar * 200 + ah * 96];
#pragma unroll
      for (int q = 0; q < 12; ++q) da[q] = ra[q];
      float4* db = (float4*)&sB[br * 200 + bc * 8];
#pragma unroll
      for (int q = 0; q < 3; ++q) db[q] = rb[q];
    }
    __syncthreads();

    const short* pa0 = &sA[(w * 32 + l16) * 200 + quad * 8];
    const short* pa1 = pa0 + 16 * 200;
    const short* pb0 = &sB[l16 * 200 + quad * 8];
    const short* pb1 = pb0 + 16 * 200;
#pragma unroll
    for (int ks = 0; ks < 6; ++ks) {
      short8 aF0 = *(const short8*)&pa0[ks * 32];
      short8 aF1 = *(const short8*)&pa1[ks * 32];
      short8 bF0 = *(const short8*)&pb0[ks * 32];
      short8 bF1 = *(const short8*)&pb1[ks * 32];
      acc[0][0] = __builtin_amdgcn_mfma_f32_16x16x32_bf16(aF0, bF0, acc[0][0], 0, 0, 0);
      acc[0][1] = __builtin_amdgcn_mfma_f32_16x16x32_bf16(aF0, bF1, acc[0][1], 0, 0, 0);
      acc[1][0] = __builtin_amdgcn_mfma_f32_16x16x32_bf16(aF1, bF0, acc[1][0], 0, 0, 0);
      acc[1][1] = __builtin_amdgcn_mfma_f32_16x16x32_bf16(aF1, bF1, acc[1][1], 0, 0, 0);
    }
  }

#pragma unroll
  for (int ni = 0; ni < 2; ++ni) {
    const int n_g = out0 + ni * 16 + l16;
    const float vb = bb[n_g];
    const float sc = gg[n_g] * rsqrtf(vv[n_g] + EPS_BN);
    const float mu = mm[n_g];
    const float vbe = be[n_g];
#pragma unroll
    for (int mi = 0; mi < 2; ++mi) {
#pragma unroll
      for (int r = 0; r < 4; ++r) {
        const int m_g = row0 + w * 32 + mi * 16 + quad * 4 + r;
        float y = acc[mi][ni][r] + vb;
        float o = (y - mu) * sc + vbe;
        float val;
        if (MODE == 0) {
          val = lrelu(o) + resid[(size_t)m_g * 288 + n_g];
        } else {
          val = fmaxf(o, 0.f);
        }
        out[(size_t)m_g * 288 + n_g] = __float2bfloat16(val);
      }
    }
  }
}

// ---------------- K4: out = h @ cl_W2.T + cl_b2 (8192x288x2), h bf16 --------
__global__ __launch_bounds__(256) void k4_out(
    const __hip_bfloat16* __restrict__ h, const float* __restrict__ w2,
    const float* __restrict__ b2, float* __restrict__ out) {
  const int wave = threadIdx.x >> 6;
  const int lane = threadIdx.x & 63;
  const int row = blockIdx.x * 4 + wave;
  const __hip_bfloat16* hr = h + (size_t)row * 288;
  float a0 = 0.f, a1 = 0.f;
#pragma unroll
  for (int i = 0; i < 5; ++i) {
    int k = lane + 64 * i;
    if (k < 288) {
      float hv = __bfloat162float(hr[k]);
      a0 = fmaf(hv, w2[k], a0);
      a1 = fmaf(hv, w2[288 + k], a1);
    }
  }
#pragma unroll
  for (int off = 32; off; off >>= 1) {
    a0 += __shfl_xor(a0, off, 64);
    a1 += __shfl_xor(a1, off, 64);
  }
  if (lane == 0) {
    out[row * 2 + 0] = a0 + b2[0];
    out[row * 2 + 1] = a1 + b2[1];
  }
}

extern "C" void kernel_launch(void* const* d_in, const int* in_sizes, int n_in,
                              void* d_out, int out_size, void* d_ws, size_t ws_size,
                              hipStream_t stream) {
  const float* x   = (const float*)d_in[0];
  const float* cw1 = (const float*)d_in[1];  const float* cb1 = (const float*)d_in[2];
  const float* cw2 = (const float*)d_in[3];  const float* cb2 = (const float*)d_in[4];
  const float* cw3 = (const float*)d_in[5];  const float* cb3 = (const float*)d_in[6];
  const float* cw4 = (const float*)d_in[7];  const float* cb4 = (const float*)d_in[8];
  const float* cw5 = (const float*)d_in[9];  const float* cb5 = (const float*)d_in[10];
  const float* cw6 = (const float*)d_in[11]; const float* cb6 = (const float*)d_in[12];
  const float* deW = (const float*)d_in[13]; const float* deb = (const float*)d_in[14];
  const float* rsW = (const float*)d_in[15]; const float* rsb = (const float*)d_in[16];
  const float* rsg = (const float*)d_in[17]; const float* rsbe = (const float*)d_in[18];
  const float* rsm = (const float*)d_in[19]; const float* rsv = (const float*)d_in[20];
  const float* clW1 = (const float*)d_in[21]; const float* clb1 = (const float*)d_in[22];
  const float* clg = (const float*)d_in[23]; const float* clbe = (const float*)d_in[24];
  const float* clm = (const float*)d_in[25]; const float* clv = (const float*)d_in[26];
  const float* clW2 = (const float*)d_in[27]; const float* clb2 = (const float*)d_in[28];

  short* ws   = (short*)d_ws;
  short* epre = ws;                        // 16384*192 bf16
  short* h    = ws;                        // reuse after K2 consumed epre
  short* ce   = ws + 16384 * 192;          // 16384*288 bf16
  short* wB2  = ce + 16384 * 288;          // 288*192 bf16
  short* wB3  = wB2 + 288 * 192;           // 288*576 bf16

  hipLaunchKernelGGL(k0_cast, dim3(128), dim3(256), 0, stream,
                     rsW, clW1, (__hip_bfloat16*)wB2, (__hip_bfloat16*)wB3);
  hipLaunchKernelGGL(k1_persample, dim3(16384), dim3(256), 0, stream, x,
                     cw1, cb1, cw2, cb2, cw3, cb3, cw4, cb4, cw5, cb5, cw6, cb6,
                     deW, deb, (__hip_bfloat16*)epre);
  // K2: M=16384, K=192, A=epre -> ce (bf16), residual x
  hipLaunchKernelGGL((gemm_mfma<192, 0>), dim3(128 * 9), dim3(256), 0, stream,
                     epre, wB2, rsb, rsg, rsbe, rsm, rsv, x, (__hip_bfloat16*)ce);
  // K3: M=8192, K=576 (ce viewed as 8192x576) -> h (bf16)
  hipLaunchKernelGGL((gemm_mfma<576, 1>), dim3(64 * 9), dim3(256), 0, stream,
                     ce, wB3, clb1, clg, clbe, clm, clv, (const float*)nullptr,
                     (__hip_bfloat16*)h);
  hipLaunchKernelGGL(k4_out, dim3(2048), dim3(256), 0, stream,
                     (const __hip_bfloat16*)h, clW2, clb2, (float*)d_out);
}

// Round 6
// 216.605 us; speedup vs baseline: 1.3649x; 1.3649x over previous
//
#include <hip/hip_runtime.h>
#include <hip/hip_bf16.h>
#include <math.h>

#define FLn 96
#define SEG 288      // 3*FL
#define EPRE_DIM 192 // 2*FL
#define EPS_BN 1e-5f

typedef __attribute__((ext_vector_type(8))) short short8;
typedef __attribute__((ext_vector_type(4))) float floatx4;

__device__ __forceinline__ float lrelu(float v) { return fmaxf(v, 0.1f * v); }
__device__ __forceinline__ short f2bf(float f) {
  __hip_bfloat16 h = __float2bfloat16(f);
  return *reinterpret_cast<short*>(&h);
}

// ---------------- K0: cast GEMM weights to bf16 ([out][k] layout kept) ------
__global__ __launch_bounds__(256) void k0_cast(
    const float* __restrict__ rsW, const float* __restrict__ clW1,
    __hip_bfloat16* __restrict__ wB2, __hip_bfloat16* __restrict__ wB3) {
  int idx = blockIdx.x * 256 + threadIdx.x;
  int stride = gridDim.x * 256;
  for (int i = idx; i < 288 * 192; i += stride) wB2[i] = __float2bfloat16(rsW[i]);
  for (int i = idx; i < 288 * 576; i += stride) wB3[i] = __float2bfloat16(clW1[i]);
}

// ---------------- K1: wave-per-(sample,half), barrier-free, MFMA field ------
// Field: S(96x96) = A(96x6) @ C(6x96), A = [aPp shifts | aNp shifts],
// C = [CP;CN] pre-convolved columns. fe = lrelu(S); row/col means.
// Each wave owns one unit and a private 2048-float LDS slice. No __syncthreads.
#define O_CIN 0      // 288
#define O_ST1 288    // 288
#define O_APP 576    // 98 (pad 0,97)
#define O_ANP 674    // 98
#define O_XPP 772    // 98
#define O_XNP 870    // 98
#define O_BERT 968   // 96
#define O_WKER 1064  // 9
#define O_ABF 1088   // bf16 96x8 (384 floats) -> 1472
#define O_BBF 1472   // bf16 96x8 (384 floats) -> 1856
#define O_RP 0       // 24 groups * 68 floats (reuses dead regions; strictly after)
#define SLICE 2048

__global__ __launch_bounds__(256) void k1_persample(
    const float* __restrict__ x,
    const float* __restrict__ cw1, const float* __restrict__ cb1,
    const float* __restrict__ cw2, const float* __restrict__ cb2,
    const float* __restrict__ cw3, const float* __restrict__ cb3,
    const float* __restrict__ cw4, const float* __restrict__ cb4,
    const float* __restrict__ cw5, const float* __restrict__ cb5,
    const float* __restrict__ cw6, const float* __restrict__ cb6,
    const float* __restrict__ deW, const float* __restrict__ deb,
    __hip_bfloat16* __restrict__ epre) {
  __shared__ float sl[4 * SLICE]; // 32 KB
  const int tid = threadIdx.x;
  const int wave = tid >> 6;
  const int lane = tid & 63;
  const int quad = lane >> 4;
  const int l16 = lane & 15;
  const int unit = blockIdx.x * 4 + wave;
  float* S = sl + wave * SLICE;
  short* Ssh = (short*)S;
  const float* xrow = x + (size_t)(unit >> 1) * 576 + (unit & 1) * 288;

  // uniform scalar conv weights
  const float a0w0 = cw1[0], a0w1 = cw1[1], a0w2 = cw1[2], a0b = cb1[0];
  const float a1w0 = cw2[0], a1w1 = cw2[1], a1w2 = cw2[2], a1b = cb2[0];
  const float a2w0 = cw3[0], a2w1 = cw3[1], a2w2 = cw3[2], a2b = cb3[0];
  const float b0w0 = cw4[0], b0w1 = cw4[1], b0w2 = cw4[2], b0b = cb4[0];
  const float b1w0 = cw5[0], b1w1 = cw5[1], b1w2 = cw5[2], b1b = cb5[0];
  const float b2w0 = cw6[0], b2w1 = cw6[1], b2w2 = cw6[2], b2b = cb6[0];

  // input -> slice
  for (int t4 = lane; t4 < 72; t4 += 64)
    *(float4*)&S[O_CIN + 4 * t4] = ((const float4*)xrow)[t4];
  // zero pad slots of aPp/aNp/xpP/xnP
  if (lane < 8) S[576 + 98 * (lane >> 1) + (lane & 1) * 97] = 0.f;

  // stage-1 convs
  for (int t = lane; t < SEG; t += 64) {
    bool g1 = t >= 96, g2 = t >= 192;
    float wa = g2 ? a2w0 : (g1 ? a1w0 : a0w0);
    float wb = g2 ? a2w1 : (g1 ? a1w1 : a0w1);
    float wc = g2 ? a2w2 : (g1 ? a1w2 : a0w2);
    float bb = g2 ? a2b  : (g1 ? a1b  : a0b);
    int p = t - (g2 ? 192 : (g1 ? 96 : 0));
    float l = p > 0 ? S[O_CIN + t - 1] : 0.f;
    float m = S[O_CIN + t];
    float r = p < FLn - 1 ? S[O_CIN + t + 1] : 0.f;
    S[O_ST1 + t] = lrelu(fmaf(wa, l, fmaf(wb, m, fmaf(wc, r, bb))));
  }
  // stage-2 convs -> aPp/aNp, xpP/xnP, bert
  for (int t = lane; t < SEG; t += 64) {
    bool g1 = t >= 96, g2 = t >= 192;
    float wa = g2 ? b2w0 : (g1 ? b1w0 : b0w0);
    float wb = g2 ? b2w1 : (g1 ? b1w1 : b0w1);
    float wc = g2 ? b2w2 : (g1 ? b1w2 : b0w2);
    float bb = g2 ? b2b  : (g1 ? b1b  : b0b);
    int p = t - (g2 ? 192 : (g1 ? 96 : 0));
    float l = p > 0 ? S[O_ST1 + t - 1] : 0.f;
    float m = S[O_ST1 + t];
    float r = p < FLn - 1 ? S[O_ST1 + t + 1] : 0.f;
    float v = lrelu(fmaf(wa, l, fmaf(wb, m, fmaf(wc, r, bb))));
    if (!g1) {
      S[O_APP + 1 + p] = fmaxf(v, 0.1f * v);
      S[O_ANP + 1 + p] = fminf(v, 0.1f * v);
    } else if (!g2) {
      S[O_XPP + 1 + p] = fmaxf(v, 0.f);
      S[O_XNP + 1 + p] = fminf(v, 0.f);
    } else {
      S[O_BERT + p] = v;
    }
  }
  // per-sample 3x3 kernel: wker = lrelu(bert @ deW.T + deb); 16-lane groups 0..2
  if (quad < 3) {
    float bv[6];
#pragma unroll
    for (int k = 0; k < 6; ++k) bv[k] = S[O_BERT + l16 + 16 * k];
#pragma unroll
    for (int oi = 0; oi < 3; ++oi) {
      int o = quad * 3 + oi;
      float p = 0.f;
#pragma unroll
      for (int k = 0; k < 6; ++k) p = fmaf(bv[k], deW[o * 96 + l16 + 16 * k], p);
      p += __shfl_xor(p, 1, 16);
      p += __shfl_xor(p, 2, 16);
      p += __shfl_xor(p, 4, 16);
      p += __shfl_xor(p, 8, 16);
      if (l16 == 0) S[O_WKER + o] = lrelu(p + deb[o]);
    }
  }
  float w9[9];
#pragma unroll
  for (int q = 0; q < 9; ++q) w9[q] = S[O_WKER + q];

  // B matrix (bf16 [n][8]): rows = [CP0,CP1,CP2,CN0,CN1,CN2,0,0] per column n
  for (int t = lane; t < 96; t += 64) {
    float xp0 = S[O_XPP + t], xp1 = S[O_XPP + t + 1], xp2 = S[O_XPP + t + 2];
    float xn0 = S[O_XNP + t], xn1 = S[O_XNP + t + 1], xn2 = S[O_XNP + t + 2];
    short8 b;
#pragma unroll
    for (int d = 0; d < 3; ++d) {
      float cp = fmaf(w9[3 * d], xp0, fmaf(w9[3 * d + 1], xp1, w9[3 * d + 2] * xp2));
      float cn = fmaf(w9[3 * d], xn0, fmaf(w9[3 * d + 1], xn1, w9[3 * d + 2] * xn2));
      b[d] = f2bf(cp);
      b[3 + d] = f2bf(cn);
    }
    b[6] = 0; b[7] = 0;
    *(short8*)&Ssh[2 * O_BBF + t * 8] = b;
  }
  // A matrix (bf16 [m][8]): [aPp[m],aPp[m+1],aPp[m+2],aNp[m],aNp[m+1],aNp[m+2],0,0]
  for (int m = lane; m < 96; m += 64) {
    short8 a;
    a[0] = f2bf(S[O_APP + m]);
    a[1] = f2bf(S[O_APP + m + 1]);
    a[2] = f2bf(S[O_APP + m + 2]);
    a[3] = f2bf(S[O_ANP + m]);
    a[4] = f2bf(S[O_ANP + m + 1]);
    a[5] = f2bf(S[O_ANP + m + 2]);
    a[6] = 0; a[7] = 0;
    *(short8*)&Ssh[2 * O_ABF + m * 8] = a;
  }

  // A-fragments (K=8 real, quads 1-3 zero)
  short8 aF[6];
#pragma unroll
  for (int mt = 0; mt < 6; ++mt) {
    short8 t = *(const short8*)&Ssh[2 * O_ABF + (mt * 16 + l16) * 8];
#pragma unroll
    for (int j = 0; j < 8; ++j) aF[mt][j] = (quad == 0) ? t[j] : (short)0;
  }

  float rowpart[6][4];
#pragma unroll
  for (int mt = 0; mt < 6; ++mt)
#pragma unroll
    for (int r = 0; r < 4; ++r) rowpart[mt][r] = 0.f;
  float cs[6];
#pragma unroll
  for (int s = 0; s < 6; ++s) cs[s] = 0.f;

#pragma unroll
  for (int s = 0; s < 6; ++s) {
    short8 tb = *(const short8*)&Ssh[2 * O_BBF + (s * 16 + l16) * 8];
    short8 bF;
#pragma unroll
    for (int j = 0; j < 8; ++j) bF[j] = (quad == 0) ? tb[j] : (short)0;
    floatx4 accv[6];
#pragma unroll
    for (int mt = 0; mt < 6; ++mt)
      accv[mt] = __builtin_amdgcn_mfma_f32_16x16x32_bf16(
          aF[mt], bF, (floatx4){0.f, 0.f, 0.f, 0.f}, 0, 0, 0);
#pragma unroll
    for (int mt = 0; mt < 6; ++mt) {
#pragma unroll
      for (int r = 0; r < 4; ++r) {
        float sv = accv[mt][r];
        float f = fmaxf(sv, 0.1f * sv);
        rowpart[mt][r] += f;
        cs[s] += f;
      }
    }
  }

  // row partials -> LDS (group stride 68 floats; 16B-aligned b128 writes)
#pragma unroll
  for (int mt = 0; mt < 6; ++mt)
    *(float4*)&S[O_RP + (quad * 6 + mt) * 68 + l16 * 4] =
        make_float4(rowpart[mt][0], rowpart[mt][1], rowpart[mt][2], rowpart[mt][3]);
  // row means
  for (int i = lane; i < 96; i += 64) {
    int g = ((i >> 2) & 3) * 6 + (i >> 4);
    int r = i & 3;
    float s = 0.f;
#pragma unroll
    for (int l = 0; l < 16; ++l) s += S[O_RP + g * 68 + l * 4 + r];
    epre[(size_t)unit * EPRE_DIM + i] = __float2bfloat16(s * (1.f / FLn));
  }
  // col means
#pragma unroll
  for (int s = 0; s < 6; ++s) {
    float v = cs[s];
    v += __shfl_xor(v, 16, 64);
    v += __shfl_xor(v, 32, 64);
    if (quad == 0)
      epre[(size_t)unit * EPRE_DIM + FLn + s * 16 + l16] =
          __float2bfloat16(v * (1.f / FLn));
  }
}

// ---------------- K2/K3: bf16 MFMA GEMM, BM=128 BN=32 BK=32 (R4 proven) -----
template <int AS, int KTOT, int MODE>
__global__ __launch_bounds__(256) void gemm_mfma(
    const short* __restrict__ A, const short* __restrict__ W,
    const float* __restrict__ bb, const float* __restrict__ gg,
    const float* __restrict__ be, const float* __restrict__ mm,
    const float* __restrict__ vv,
    const float* __restrict__ resid, __hip_bfloat16* __restrict__ out) {
  __shared__ short sA[128 * 40]; // 10 KB
  __shared__ short sB[32 * 40];  // 2.5 KB
  const int tid = threadIdx.x;
  const int lane = tid & 63;
  const int w = tid >> 6;
  const int quad = lane >> 4;
  const int l16 = lane & 15;
  const int row0 = (blockIdx.x / 9) * 128;
  const int out0 = (blockIdx.x % 9) * 32;

  floatx4 acc[2][2];
#pragma unroll
  for (int mi = 0; mi < 2; ++mi)
#pragma unroll
    for (int ni = 0; ni < 2; ++ni) acc[mi][ni] = (floatx4){0.f, 0.f, 0.f, 0.f};

  const int ar = tid >> 1;
  const int ah = tid & 1;
  for (int kc = 0; kc < KTOT; kc += 32) {
    {
      const float4* src = (const float4*)&A[(size_t)(row0 + ar) * AS + kc + ah * 16];
      float4 v0 = src[0];
      float4 v1 = src[1];
      *(float4*)&sA[ar * 40 + ah * 16] = v0;
      *(float4*)&sA[ar * 40 + ah * 16 + 8] = v1;
      if (tid < 64) {
        const float4* bs = (const float4*)&W[(size_t)(out0 + ar) * KTOT + kc + ah * 16];
        float4 u0 = bs[0];
        float4 u1 = bs[1];
        *(float4*)&sB[ar * 40 + ah * 16] = u0;
        *(float4*)&sB[ar * 40 + ah * 16 + 8] = u1;
      }
    }
    __syncthreads();
    short8 aF0 = *(const short8*)&sA[(w * 32 + l16) * 40 + quad * 8];
    short8 aF1 = *(const short8*)&sA[(w * 32 + 16 + l16) * 40 + quad * 8];
    short8 bF0 = *(const short8*)&sB[l16 * 40 + quad * 8];
    short8 bF1 = *(const short8*)&sB[(16 + l16) * 40 + quad * 8];
    acc[0][0] = __builtin_amdgcn_mfma_f32_16x16x32_bf16(aF0, bF0, acc[0][0], 0, 0, 0);
    acc[0][1] = __builtin_amdgcn_mfma_f32_16x16x32_bf16(aF0, bF1, acc[0][1], 0, 0, 0);
    acc[1][0] = __builtin_amdgcn_mfma_f32_16x16x32_bf16(aF1, bF0, acc[1][0], 0, 0, 0);
    acc[1][1] = __builtin_amdgcn_mfma_f32_16x16x32_bf16(aF1, bF1, acc[1][1], 0, 0, 0);
    __syncthreads();
  }

#pragma unroll
  for (int ni = 0; ni < 2; ++ni) {
    const int n_g = out0 + ni * 16 + l16;
    const float vb = bb[n_g];
    const float sc = gg[n_g] * rsqrtf(vv[n_g] + EPS_BN);
    const float mu = mm[n_g];
    const float vbe = be[n_g];
#pragma unroll
    for (int mi = 0; mi < 2; ++mi) {
#pragma unroll
      for (int r = 0; r < 4; ++r) {
        const int m_g = row0 + w * 32 + mi * 16 + quad * 4 + r;
        float y = acc[mi][ni][r] + vb;
        float o = (y - mu) * sc + vbe;
        float val;
        if (MODE == 0) {
          val = lrelu(o) + resid[(size_t)m_g * 288 + n_g];
        } else {
          val = fmaxf(o, 0.f);
        }
        out[(size_t)m_g * 288 + n_g] = __float2bfloat16(val);
      }
    }
  }
}

// ---------------- K4: out = h @ cl_W2.T + cl_b2 (8192x288x2), h bf16 --------
__global__ __launch_bounds__(256) void k4_out(
    const __hip_bfloat16* __restrict__ h, const float* __restrict__ w2,
    const float* __restrict__ b2, float* __restrict__ out) {
  const int wave = threadIdx.x >> 6;
  const int lane = threadIdx.x & 63;
  const int row = blockIdx.x * 4 + wave;
  const __hip_bfloat16* hr = h + (size_t)row * 288;
  float a0 = 0.f, a1 = 0.f;
#pragma unroll
  for (int i = 0; i < 5; ++i) {
    int k = lane + 64 * i;
    if (k < 288) {
      float hv = __bfloat162float(hr[k]);
      a0 = fmaf(hv, w2[k], a0);
      a1 = fmaf(hv, w2[288 + k], a1);
    }
  }
#pragma unroll
  for (int off = 32; off; off >>= 1) {
    a0 += __shfl_xor(a0, off, 64);
    a1 += __shfl_xor(a1, off, 64);
  }
  if (lane == 0) {
    out[row * 2 + 0] = a0 + b2[0];
    out[row * 2 + 1] = a1 + b2[1];
  }
}

extern "C" void kernel_launch(void* const* d_in, const int* in_sizes, int n_in,
                              void* d_out, int out_size, void* d_ws, size_t ws_size,
                              hipStream_t stream) {
  const float* x   = (const float*)d_in[0];
  const float* cw1 = (const float*)d_in[1];  const float* cb1 = (const float*)d_in[2];
  const float* cw2 = (const float*)d_in[3];  const float* cb2 = (const float*)d_in[4];
  const float* cw3 = (const float*)d_in[5];  const float* cb3 = (const float*)d_in[6];
  const float* cw4 = (const float*)d_in[7];  const float* cb4 = (const float*)d_in[8];
  const float* cw5 = (const float*)d_in[9];  const float* cb5 = (const float*)d_in[10];
  const float* cw6 = (const float*)d_in[11]; const float* cb6 = (const float*)d_in[12];
  const float* deW = (const float*)d_in[13]; const float* deb = (const float*)d_in[14];
  const float* rsW = (const float*)d_in[15]; const float* rsb = (const float*)d_in[16];
  const float* rsg = (const float*)d_in[17]; const float* rsbe = (const float*)d_in[18];
  const float* rsm = (const float*)d_in[19]; const float* rsv = (const float*)d_in[20];
  const float* clW1 = (const float*)d_in[21]; const float* clb1 = (const float*)d_in[22];
  const float* clg = (const float*)d_in[23]; const float* clbe = (const float*)d_in[24];
  const float* clm = (const float*)d_in[25]; const float* clv = (const float*)d_in[26];
  const float* clW2 = (const float*)d_in[27]; const float* clb2 = (const float*)d_in[28];

  short* ws   = (short*)d_ws;
  short* epre = ws;                        // 16384*192 bf16
  short* h    = ws;                        // reuse after K2 consumed epre
  short* ce   = ws + 16384 * 192;          // 16384*288 bf16
  short* wB2  = ce + 16384 * 288;          // 288*192 bf16
  short* wB3  = wB2 + 288 * 192;           // 288*576 bf16

  hipLaunchKernelGGL(k0_cast, dim3(128), dim3(256), 0, stream,
                     rsW, clW1, (__hip_bfloat16*)wB2, (__hip_bfloat16*)wB3);
  hipLaunchKernelGGL(k1_persample, dim3(4096), dim3(256), 0, stream, x,
                     cw1, cb1, cw2, cb2, cw3, cb3, cw4, cb4, cw5, cb5, cw6, cb6,
                     deW, deb, (__hip_bfloat16*)epre);
  // K2: M=16384, K=192, A=epre -> ce (bf16), residual x
  hipLaunchKernelGGL((gemm_mfma<192, 192, 0>), dim3(128 * 9), dim3(256), 0, stream,
                     epre, wB2, rsb, rsg, rsbe, rsm, rsv, x, (__hip_bfloat16*)ce);
  // K3: M=8192, K=576 (ce viewed as 8192x576) -> h (bf16)
  hipLaunchKernelGGL((gemm_mfma<576, 576, 1>), dim3(64 * 9), dim3(256), 0, stream,
                     ce, wB3, clb1, clg, clbe, clm, clv, (const float*)nullptr,
                     (__hip_bfloat16*)h);
  hipLaunchKernelGGL(k4_out, dim3(2048), dim3(256), 0, stream,
                     (const __hip_bfloat16*)h, clW2, clb2, (float*)d_out);
}